// Round 6
// baseline (746.550 us; speedup 1.0000x reference)
//
#include <hip/hip_runtime.h>
#include <hip/hip_bf16.h>
#include <math.h>

#define NN   50000
#define NE   800000
#define NHEAD 4
#define HIDD 64
#define DD   256   // NHEAD*HIDD
#define NCLS 40

typedef __attribute__((ext_vector_type(8))) short s8v;    // 8 x bf16 bits
typedef __attribute__((ext_vector_type(4))) float f4v;

static __device__ __forceinline__ float elu_f(float x) {
  return x > 0.f ? x : expm1f(x);
}
static __device__ __forceinline__ float lrelu_exp(float x) {
  float v = x > 0.f ? x : 0.01f * x;
  return expf(v);
}
static __device__ __forceinline__ unsigned short f2bf(float x) {
  union { float f; unsigned u; } v; v.f = x;
  unsigned r = v.u + 0x7fffu + ((v.u >> 16) & 1u);   // RNE
  return (unsigned short)(r >> 16);
}
static __device__ __forceinline__ float bf2f(unsigned short b) {
  union { unsigned u; float f; } v; v.u = ((unsigned)b) << 16;
  return v.f;
}
static __device__ __forceinline__ float rdlanef(float v, int l) {
  return __uint_as_float(__builtin_amdgcn_readlane(__float_as_uint(v), l));
}

// ---- one launch packs all 5 weight matrices to bf16 hi/lo [n][k] layout
__global__ void pack_all(const float* __restrict__ W0, const float* __restrict__ W1,
                         const float* __restrict__ R1, const float* __restrict__ Wf,
                         const float* __restrict__ Rf,
                         unsigned short* __restrict__ Wp0h, unsigned short* __restrict__ Wp0l,
                         unsigned short* __restrict__ Wp1h, unsigned short* __restrict__ Wp1l,
                         unsigned short* __restrict__ Rp1h, unsigned short* __restrict__ Rp1l,
                         unsigned short* __restrict__ Wfh, unsigned short* __restrict__ Wfl,
                         unsigned short* __restrict__ Rfh, unsigned short* __restrict__ Rfl) {
  int bid = blockIdx.x;
  const float* S; unsigned short *Bh, *Bl; int big;
  if (bid < 256)      { S = W0; Bh = Wp0h; Bl = Wp0l; big = 1; }
  else if (bid < 512) { S = W1; Bh = Wp1h; Bl = Wp1l; big = 1; bid -= 256; }
  else if (bid < 768) { S = R1; Bh = Rp1h; Bl = Rp1l; big = 1; bid -= 512; }
  else if (bid < 832) { S = Wf; Bh = Wfh;  Bl = Wfl;  big = 0; bid -= 768; }
  else                { S = Rf; Bh = Rfh;  Bl = Rfl;  big = 0; bid -= 832; }
  int i = bid * 256 + threadIdx.x;       // i = n*256 + k
  int n = i >> 8, k = i & 255;
  float v;
  if (big) v = S[(n >> 6) * (256 * 64) + k * 64 + (n & 63)];        // [H][256][64]
  else     v = (n < NCLS) ? S[k * NCLS + n] : 0.f;                  // [256][40]
  unsigned short hi = f2bf(v);
  Bh[i] = hi;
  Bl[i] = f2bf(v - bf2f(hi));
}

// ---- split fp32 [*][256] -> bf16 hi/lo (features only; layer outputs fuse this)
__global__ void split_bf(const float* __restrict__ A,
                         unsigned short* __restrict__ Ah,
                         unsigned short* __restrict__ Al, int n4) {
  int i = blockIdx.x * 256 + threadIdx.x;
  if (i >= n4) return;
  float4 v = ((const float4*)A)[i];
  ushort4 h, l;
  h.x = f2bf(v.x); l.x = f2bf(v.x - bf2f(h.x));
  h.y = f2bf(v.y); l.y = f2bf(v.y - bf2f(h.y));
  h.z = f2bf(v.z); l.z = f2bf(v.z - bf2f(h.z));
  h.w = f2bf(v.w); l.w = f2bf(v.w - bf2f(h.w));
  ((ushort4*)Ah)[i] = h;
  ((ushort4*)Al)[i] = l;
}

// ---- bf16x3 MFMA GEMM: C[M x Nc] = A[M x 256] @ Bt^T + bias
// A pre-split into Ah/Al bf16 [M][256]; Bt stored [Npad][256] bf16 (hi,lo).
// OBF=1: write bf16 to Cb; OBF=0: write fp32 to C.
template <int BN, int OBF>
__global__ __launch_bounds__(256) void gemm_bf16x3(
    const unsigned short* __restrict__ Ah, const unsigned short* __restrict__ Al,
    const unsigned short* __restrict__ Bth, const unsigned short* __restrict__ Btl,
    const float* __restrict__ bias, float* __restrict__ C,
    unsigned short* __restrict__ Cb,
    int M, int Nc) {
  constexpr int K = 256;
  constexpr int RS = 40;                 // LDS row stride (ushorts): 80B -> 2-way max
  constexpr int WM = (BN == 128) ? 2 : 4;   // waves along M
  constexpr int WN = 4 / WM;                // waves along N
  constexpr int MI = (128 / WM) / 16;       // 4 or 2
  constexpr int NI = (BN / WN) / 16;        // 4

  __shared__ unsigned short sAh[128 * RS];
  __shared__ unsigned short sAl[128 * RS];
  __shared__ unsigned short sBh[BN * RS];
  __shared__ unsigned short sBl[BN * RS];

  const int tid = threadIdx.x;
  const int lane = tid & 63;
  const int w = tid >> 6;
  const int wr = w / WN, wc = w % WN;
  const int rowbase = wr * (128 / WM);
  const int colbase = wc * (BN / WN);
  const int row0 = blockIdx.x * 128;
  const int col0 = blockIdx.y * BN;
  const int lm = lane & 15;
  const int lk8 = (lane >> 4) * 8;

  f4v acc[MI][NI];
#pragma unroll
  for (int i = 0; i < MI; i++)
#pragma unroll
    for (int j = 0; j < NI; j++) acc[i][j] = (f4v)(0.f);

  for (int k0 = 0; k0 < K; k0 += 32) {
    __syncthreads();
    // stage A 128x32 bf16 hi/lo (pre-split)
#pragma unroll
    for (int i = 0; i < 2; ++i) {
      int idx = tid + i * 256;            // 0..511
      int r = idx >> 2, seg = idx & 3;
      int grow = row0 + r;
      s8v hv = (s8v)(short)0, lv = (s8v)(short)0;
      if (grow < M) {
        size_t g = (size_t)grow * K + k0 + seg * 8;
        hv = *(const s8v*)(Ah + g);
        lv = *(const s8v*)(Al + g);
      }
      *(s8v*)&sAh[r * RS + seg * 8] = hv;
      *(s8v*)&sAl[r * RS + seg * 8] = lv;
    }
    // stage B BNx32 bf16 hi/lo (pre-transposed [n][k])
#pragma unroll
    for (int i = 0; i < BN / 64; ++i) {
      int idx = tid + i * 256;            // < BN*4
      int n = idx >> 2, seg = idx & 3;
      size_t g = (size_t)(col0 + n) * K + k0 + seg * 8;
      *(s8v*)&sBh[n * RS + seg * 8] = *(const s8v*)(Bth + g);
      *(s8v*)&sBl[n * RS + seg * 8] = *(const s8v*)(Btl + g);
    }
    __syncthreads();

    s8v ah[MI], al_[MI], bh[NI], bl_[NI];
#pragma unroll
    for (int mi = 0; mi < MI; ++mi) {
      int base = (rowbase + mi * 16 + lm) * RS + lk8;
      ah[mi] = *(const s8v*)&sAh[base];
      al_[mi] = *(const s8v*)&sAl[base];
    }
#pragma unroll
    for (int ni = 0; ni < NI; ++ni) {
      int base = (colbase + ni * 16 + lm) * RS + lk8;
      bh[ni] = *(const s8v*)&sBh[base];
      bl_[ni] = *(const s8v*)&sBl[base];
    }
    // pass 1: hi*hi
#pragma unroll
    for (int mi = 0; mi < MI; ++mi)
#pragma unroll
      for (int ni = 0; ni < NI; ++ni)
        acc[mi][ni] = __builtin_amdgcn_mfma_f32_16x16x32_bf16(ah[mi], bh[ni], acc[mi][ni], 0, 0, 0);
    // pass 2: hi*lo
#pragma unroll
    for (int mi = 0; mi < MI; ++mi)
#pragma unroll
      for (int ni = 0; ni < NI; ++ni)
        acc[mi][ni] = __builtin_amdgcn_mfma_f32_16x16x32_bf16(ah[mi], bl_[ni], acc[mi][ni], 0, 0, 0);
    // pass 3: lo*hi
#pragma unroll
    for (int mi = 0; mi < MI; ++mi)
#pragma unroll
      for (int ni = 0; ni < NI; ++ni)
        acc[mi][ni] = __builtin_amdgcn_mfma_f32_16x16x32_bf16(al_[mi], bh[ni], acc[mi][ni], 0, 0, 0);
  }

  // epilogue: C = acc + bias  (D map: col=lane&15, row=(lane>>4)*4+r)
#pragma unroll
  for (int ni = 0; ni < NI; ++ni) {
    int col = col0 + colbase + ni * 16 + lm;
    if (col >= Nc) continue;
    float bv = bias[col];
#pragma unroll
    for (int mi = 0; mi < MI; ++mi) {
      int rbase = row0 + rowbase + mi * 16 + (lane >> 4) * 4;
#pragma unroll
      for (int r = 0; r < 4; ++r) {
        int row = rbase + r;
        if (row < M) {
          float o = acc[mi][ni][r] + bv;
          if (OBF) Cb[(size_t)row * Nc + col] = f2bf(o);
          else     C[(size_t)row * Nc + col] = o;
        }
      }
    }
  }
}

// ---- per-node attention scores from bf16 ft, 4 heads over 256 dims
__global__ void attn_scores4_bf(const unsigned short* __restrict__ ftb,
                                const float* __restrict__ al, const float* __restrict__ alb,
                                const float* __restrict__ ar, const float* __restrict__ arb,
                                float* __restrict__ a1, float* __restrict__ a2, int n_nodes) {
  int n = blockIdx.x * 4 + (threadIdx.x >> 6);
  if (n >= n_nodes) return;
  int lane = threadIdx.x & 63;
  ushort4 fb = *(const ushort4*)(ftb + (size_t)n * 256 + lane * 4);
  float4 f = make_float4(bf2f(fb.x), bf2f(fb.y), bf2f(fb.z), bf2f(fb.w));
  float4 l4 = *(const float4*)(al + lane * 4);
  float4 r4 = *(const float4*)(ar + lane * 4);
  float p1 = f.x * l4.x + f.y * l4.y + f.z * l4.z + f.w * l4.w;
  float p2 = f.x * r4.x + f.y * r4.y + f.z * r4.z + f.w * r4.w;
#pragma unroll
  for (int m = 1; m < 16; m <<= 1) {
    p1 += __shfl_xor(p1, m);
    p2 += __shfl_xor(p2, m);
  }
  if ((lane & 15) == 0) {
    int h = lane >> 4;
    a1[n * 4 + h] = p1 + alb[h];
    a2[n * 4 + h] = p2 + arb[h];
  }
}

// ---- final-layer attention scores (1 head over 40 dims, fp32 ft)
__global__ void attn_scores1(const float* __restrict__ ftf,
                             const float* __restrict__ alf, const float* __restrict__ alfb,
                             const float* __restrict__ arf, const float* __restrict__ arfb,
                             float* __restrict__ a1, float* __restrict__ a2, int n_nodes) {
  int n = blockIdx.x * 4 + (threadIdx.x >> 6);
  if (n >= n_nodes) return;
  int lane = threadIdx.x & 63;
  float v = (lane < NCLS) ? ftf[(size_t)n * NCLS + lane] : 0.f;
  float p1 = (lane < NCLS) ? v * alf[lane] : 0.f;
  float p2 = (lane < NCLS) ? v * arf[lane] : 0.f;
#pragma unroll
  for (int m = 1; m < 64; m <<= 1) {
    p1 += __shfl_xor(p1, m);
    p2 += __shfl_xor(p2, m);
  }
  if (lane == 0) {
    a1[n] = p1 + alfb[0];
    a2[n] = p2 + arfb[0];
  }
}

// ---- CSR build
__global__ void count_deg(const int* __restrict__ dst, int* __restrict__ deg) {
  int e = blockIdx.x * blockDim.x + threadIdx.x;
  if (e < NE) atomicAdd(&deg[dst[e]], 1);
}

// scan + also emit cursor (= row start) so no separate copy pass
__global__ void scan_deg(const int* __restrict__ deg, int* __restrict__ row_ptr,
                         int* __restrict__ cursor, int n) {
  __shared__ int partials[1024];
  int t = threadIdx.x;
  int chunk = (n + 1023) >> 10;
  int base = t * chunk;
  int lim = min(base + chunk, n);
  int sum = 0;
  for (int i = base; i < lim; ++i) sum += deg[i];
  partials[t] = sum;
  __syncthreads();
  for (int off = 1; off < 1024; off <<= 1) {
    int v = (t >= off) ? partials[t - off] : 0;
    __syncthreads();
    partials[t] += v;
    __syncthreads();
  }
  int run = (t == 0) ? 0 : partials[t - 1];
  if (t == 0) row_ptr[0] = 0;
  for (int i = base; i < lim; ++i) {
    cursor[i] = run;
    run += deg[i];
    row_ptr[i + 1] = run;
  }
}

__global__ void scatter_e(const int* __restrict__ dst, int* __restrict__ cursor,
                          int* __restrict__ eidx) {
  int e = blockIdx.x * blockDim.x + threadIdx.x;
  if (e >= NE) return;
  int d = dst[e];
  int pos = atomicAdd(&cursor[d], 1);
  eidx[pos] = e;
}

// ---- wave-per-node fused gather (4 heads, D=256), bf16 ft.
// Per chunk: lane e computes the 4 head-weights for edge e into LDS; inner
// loop (8x unrolled) reads my-head weight via broadcast ds_read and src via
// readlane (SGPR -> SALU addressing). Writes hi/lo bf16 split directly.
__global__ __launch_bounds__(256) void gather_wave4(
    const unsigned short* __restrict__ ftb, const float* __restrict__ a1,
    const float* __restrict__ a2, const float* __restrict__ res,
    const int* __restrict__ row_ptr, const int* __restrict__ eidx,
    const int* __restrict__ src,
    unsigned short* __restrict__ outh, unsigned short* __restrict__ outl) {
  __shared__ float s_w[4][64][4];
  const int wid = threadIdx.x >> 6;
  const int n = blockIdx.x * 4 + wid;
  if (n >= NN) return;
  const int lane = threadIdx.x & 63;
  const int h = lane >> 4;            // head for my 4 columns
  const int b = row_ptr[n], en = row_ptr[n + 1];
  const int deg = en - b;
  const float4 a1v = *(const float4*)(a1 + (size_t)n * 4);
  float4 accv = make_float4(0.f, 0.f, 0.f, 0.f);
  float den = 0.f;

  for (int cb = 0; cb < deg; cb += 64) {
    int cnt = min(64, deg - cb);
    int s = 0;
    if (lane < cnt) {
      s = src[eidx[b + cb + lane]];
      float4 as_ = *(const float4*)(a2 + (size_t)s * 4);
      float4 w4;
      w4.x = lrelu_exp(as_.x + a1v.x);
      w4.y = lrelu_exp(as_.y + a1v.y);
      w4.z = lrelu_exp(as_.z + a1v.z);
      w4.w = lrelu_exp(as_.w + a1v.w);
      *(float4*)&s_w[wid][lane][0] = w4;
    }
    // same-wave LDS RAW: drain DS queue (no block barrier -- waves have
    // unequal trip counts)
    asm volatile("s_waitcnt lgkmcnt(0)" ::: "memory");
    int i = 0;
    for (; i + 8 <= cnt; i += 8) {
      int s0 = __builtin_amdgcn_readlane(s, i + 0);
      int s1 = __builtin_amdgcn_readlane(s, i + 1);
      int s2 = __builtin_amdgcn_readlane(s, i + 2);
      int s3 = __builtin_amdgcn_readlane(s, i + 3);
      int s4 = __builtin_amdgcn_readlane(s, i + 4);
      int s5 = __builtin_amdgcn_readlane(s, i + 5);
      int s6 = __builtin_amdgcn_readlane(s, i + 6);
      int s7 = __builtin_amdgcn_readlane(s, i + 7);
      float w0 = s_w[wid][i + 0][h];
      float w1 = s_w[wid][i + 1][h];
      float w2 = s_w[wid][i + 2][h];
      float w3 = s_w[wid][i + 3][h];
      float w4_ = s_w[wid][i + 4][h];
      float w5 = s_w[wid][i + 5][h];
      float w6 = s_w[wid][i + 6][h];
      float w7 = s_w[wid][i + 7][h];
      ushort4 f0 = *(const ushort4*)(ftb + (size_t)s0 * DD + lane * 4);
      ushort4 f1 = *(const ushort4*)(ftb + (size_t)s1 * DD + lane * 4);
      ushort4 f2 = *(const ushort4*)(ftb + (size_t)s2 * DD + lane * 4);
      ushort4 f3 = *(const ushort4*)(ftb + (size_t)s3 * DD + lane * 4);
      ushort4 f4 = *(const ushort4*)(ftb + (size_t)s4 * DD + lane * 4);
      ushort4 f5 = *(const ushort4*)(ftb + (size_t)s5 * DD + lane * 4);
      ushort4 f6 = *(const ushort4*)(ftb + (size_t)s6 * DD + lane * 4);
      ushort4 f7 = *(const ushort4*)(ftb + (size_t)s7 * DD + lane * 4);
      accv.x = fmaf(bf2f(f0.x), w0, accv.x);
      accv.y = fmaf(bf2f(f0.y), w0, accv.y);
      accv.z = fmaf(bf2f(f0.z), w0, accv.z);
      accv.w = fmaf(bf2f(f0.w), w0, accv.w);
      accv.x = fmaf(bf2f(f1.x), w1, accv.x);
      accv.y = fmaf(bf2f(f1.y), w1, accv.y);
      accv.z = fmaf(bf2f(f1.z), w1, accv.z);
      accv.w = fmaf(bf2f(f1.w), w1, accv.w);
      accv.x = fmaf(bf2f(f2.x), w2, accv.x);
      accv.y = fmaf(bf2f(f2.y), w2, accv.y);
      accv.z = fmaf(bf2f(f2.z), w2, accv.z);
      accv.w = fmaf(bf2f(f2.w), w2, accv.w);
      accv.x = fmaf(bf2f(f3.x), w3, accv.x);
      accv.y = fmaf(bf2f(f3.y), w3, accv.y);
      accv.z = fmaf(bf2f(f3.z), w3, accv.z);
      accv.w = fmaf(bf2f(f3.w), w3, accv.w);
      accv.x = fmaf(bf2f(f4.x), w4_, accv.x);
      accv.y = fmaf(bf2f(f4.y), w4_, accv.y);
      accv.z = fmaf(bf2f(f4.z), w4_, accv.z);
      accv.w = fmaf(bf2f(f4.w), w4_, accv.w);
      accv.x = fmaf(bf2f(f5.x), w5, accv.x);
      accv.y = fmaf(bf2f(f5.y), w5, accv.y);
      accv.z = fmaf(bf2f(f5.z), w5, accv.z);
      accv.w = fmaf(bf2f(f5.w), w5, accv.w);
      accv.x = fmaf(bf2f(f6.x), w6, accv.x);
      accv.y = fmaf(bf2f(f6.y), w6, accv.y);
      accv.z = fmaf(bf2f(f6.z), w6, accv.z);
      accv.w = fmaf(bf2f(f6.w), w6, accv.w);
      accv.x = fmaf(bf2f(f7.x), w7, accv.x);
      accv.y = fmaf(bf2f(f7.y), w7, accv.y);
      accv.z = fmaf(bf2f(f7.z), w7, accv.z);
      accv.w = fmaf(bf2f(f7.w), w7, accv.w);
      den += ((w0 + w1) + (w2 + w3)) + ((w4_ + w5) + (w6 + w7));
    }
    for (; i < cnt; ++i) {
      int si = __builtin_amdgcn_readlane(s, i);
      float wi = s_w[wid][i][h];
      ushort4 fv = *(const ushort4*)(ftb + (size_t)si * DD + lane * 4);
      accv.x = fmaf(bf2f(fv.x), wi, accv.x);
      accv.y = fmaf(bf2f(fv.y), wi, accv.y);
      accv.z = fmaf(bf2f(fv.z), wi, accv.z);
      accv.w = fmaf(bf2f(fv.w), wi, accv.w);
      den += wi;
    }
    // WAR on s_w across chunks handled by in-order per-wave DS pipe + the
    // lgkmcnt(0) at the top of the next iteration.
  }
  float invden = (deg > 0) ? 1.f / den : 0.f;
  float4 r = (res != nullptr) ? *(const float4*)(res + (size_t)n * DD + lane * 4)
                              : make_float4(0.f, 0.f, 0.f, 0.f);
  float4 o;
  o.x = elu_f(r.x + accv.x * invden);
  o.y = elu_f(r.y + accv.y * invden);
  o.z = elu_f(r.z + accv.z * invden);
  o.w = elu_f(r.w + accv.w * invden);
  ushort4 hh, ll;
  hh.x = f2bf(o.x); ll.x = f2bf(o.x - bf2f(hh.x));
  hh.y = f2bf(o.y); ll.y = f2bf(o.y - bf2f(hh.y));
  hh.z = f2bf(o.z); ll.z = f2bf(o.z - bf2f(hh.z));
  hh.w = f2bf(o.w); ll.w = f2bf(o.w - bf2f(hh.w));
  *(ushort4*)(outh + (size_t)n * DD + lane * 4) = hh;
  *(ushort4*)(outl + (size_t)n * DD + lane * 4) = ll;
}

// ---- fused gather (1 head, D=NCLS=40), fp32 ft, 8x-unrolled
__global__ __launch_bounds__(64) void gather_fused1(
    const float* __restrict__ ft, const float* __restrict__ a1,
    const float* __restrict__ a2, const float* __restrict__ res,
    const int* __restrict__ row_ptr, const int* __restrict__ eidx,
    const int* __restrict__ src, float* __restrict__ out) {
  const int n = blockIdx.x;
  const int d = threadIdx.x;
  const int b = row_ptr[n], en = row_ptr[n + 1];
  const int deg = en - b;
  const float a1n = a1[n];
  float acc = 0.f;
  float den = 0.f;

  for (int cb = 0; cb < deg; cb += 64) {
    int cnt = min(64, deg - cb);
    int s = 0;
    float wv = 0.f;
    if (d < cnt) {
      s = src[eidx[b + cb + d]];
      wv = lrelu_exp(a2[s] + a1n);
    }
    int i = 0;
    for (; i + 8 <= cnt; i += 8) {
      int s0 = __builtin_amdgcn_readlane(s, i + 0);
      int s1 = __builtin_amdgcn_readlane(s, i + 1);
      int s2 = __builtin_amdgcn_readlane(s, i + 2);
      int s3 = __builtin_amdgcn_readlane(s, i + 3);
      int s4 = __builtin_amdgcn_readlane(s, i + 4);
      int s5 = __builtin_amdgcn_readlane(s, i + 5);
      int s6 = __builtin_amdgcn_readlane(s, i + 6);
      int s7 = __builtin_amdgcn_readlane(s, i + 7);
      float w0 = rdlanef(wv, i + 0), w1 = rdlanef(wv, i + 1);
      float w2 = rdlanef(wv, i + 2), w3 = rdlanef(wv, i + 3);
      float w4_ = rdlanef(wv, i + 4), w5 = rdlanef(wv, i + 5);
      float w6 = rdlanef(wv, i + 6), w7 = rdlanef(wv, i + 7);
      if (d < NCLS) {
        float v0 = ft[(size_t)s0 * NCLS + d];
        float v1 = ft[(size_t)s1 * NCLS + d];
        float v2 = ft[(size_t)s2 * NCLS + d];
        float v3 = ft[(size_t)s3 * NCLS + d];
        float v4 = ft[(size_t)s4 * NCLS + d];
        float v5 = ft[(size_t)s5 * NCLS + d];
        float v6 = ft[(size_t)s6 * NCLS + d];
        float v7 = ft[(size_t)s7 * NCLS + d];
        acc = fmaf(v0, w0, acc);
        acc = fmaf(v1, w1, acc);
        acc = fmaf(v2, w2, acc);
        acc = fmaf(v3, w3, acc);
        acc = fmaf(v4, w4_, acc);
        acc = fmaf(v5, w5, acc);
        acc = fmaf(v6, w6, acc);
        acc = fmaf(v7, w7, acc);
      }
      den += ((w0 + w1) + (w2 + w3)) + ((w4_ + w5) + (w6 + w7));
    }
    for (; i < cnt; ++i) {
      int si = __builtin_amdgcn_readlane(s, i);
      float wi = rdlanef(wv, i);
      if (d < NCLS) acc = fmaf(ft[(size_t)si * NCLS + d], wi, acc);
      den += wi;
    }
  }
  float invden = (deg > 0) ? 1.f / den : 0.f;
  if (d < NCLS) {
    float r = res[(size_t)n * NCLS + d];
    out[(size_t)n * NCLS + d] = elu_f(r + acc * invden);
  }
}

extern "C" void kernel_launch(void* const* d_in, const int* in_sizes, int n_in,
                              void* d_out, int out_size, void* d_ws, size_t ws_size,
                              hipStream_t stream) {
  const float* features = (const float*)d_in[0];
  const int* src = (const int*)d_in[1];
  const int* dst = (const int*)d_in[2];
  const float* W0 = (const float*)d_in[3];
  const float* b0 = (const float*)d_in[4];
  const float* al0 = (const float*)d_in[5];
  const float* alb0 = (const float*)d_in[6];
  const float* ar0 = (const float*)d_in[7];
  const float* arb0 = (const float*)d_in[8];
  const float* W1 = (const float*)d_in[9];
  const float* b1 = (const float*)d_in[10];
  const float* al1 = (const float*)d_in[11];
  const float* alb1 = (const float*)d_in[12];
  const float* ar1 = (const float*)d_in[13];
  const float* arb1 = (const float*)d_in[14];
  const float* R1 = (const float*)d_in[15];
  const float* Rb1 = (const float*)d_in[16];
  const float* Wf = (const float*)d_in[17];
  const float* bfc = (const float*)d_in[18];
  const float* alf = (const float*)d_in[19];
  const float* alfb = (const float*)d_in[20];
  const float* arf = (const float*)d_in[21];
  const float* arfb = (const float*)d_in[22];
  const float* Rf = (const float*)d_in[23];
  const float* Rbf = (const float*)d_in[24];
  float* out = (float*)d_out;

  float* p = (float*)d_ws;
  float* B1 = p;  p += (size_t)NN * 256;   // final ft (fp32, 40 cols used)
  float* B2 = p;  p += (size_t)NN * 256;   // final res (fp32, 40 cols used)
  float* B3 = p;  p += (size_t)NN * 256;   // layer-1 residual (fp32)
  float* a1 = p;  p += (size_t)NN * 4;
  float* a2 = p;  p += (size_t)NN * 4;
  unsigned short* us = (unsigned short*)p;
  unsigned short* Wp0h = us; us += 65536;
  unsigned short* Wp0l = us; us += 65536;
  unsigned short* Wp1h = us; us += 65536;
  unsigned short* Wp1l = us; us += 65536;
  unsigned short* Rp1h = us; us += 65536;
  unsigned short* Rp1l = us; us += 65536;
  unsigned short* Wfh = us;  us += 64 * 256;
  unsigned short* Wfl = us;  us += 64 * 256;
  unsigned short* Rfh = us;  us += 64 * 256;
  unsigned short* Rfl = us;  us += 64 * 256;
  unsigned short* Ah = us;   us += (size_t)NN * 256;
  unsigned short* Al = us;   us += (size_t)NN * 256;
  unsigned short* ftb = us;  us += (size_t)NN * 256;
  int* ip = (int*)us;
  int* row_ptr = ip; ip += NN + 1;
  int* cursor = ip;  ip += NN;
  int* deg = ip;     ip += NN;
  int* eidx = ip;    ip += NE;

  const int EB = (NE + 255) / 256;
  const int N4 = NN * 64;            // NN*256/4 float4 elements

  // weight packing + bf16 hi/lo split, single launch
  pack_all<<<896, 256, 0, stream>>>(W0, W1, R1, Wf, Rf,
                                    Wp0h, Wp0l, Wp1h, Wp1l, Rp1h, Rp1l,
                                    Wfh, Wfl, Rfh, Rfl);

  // CSR by dst (built once, reused by all 3 layers)
  hipMemsetAsync(deg, 0, NN * sizeof(int), stream);
  count_deg<<<EB, 256, 0, stream>>>(dst, deg);
  scan_deg<<<1, 1024, 0, stream>>>(deg, row_ptr, cursor, NN);
  scatter_e<<<EB, 256, 0, stream>>>(dst, cursor, eidx);

  const int MB = (NN + 127) / 128;   // 391
  dim3 gbig(MB, 2);
  dim3 gsm(MB, 1);
  const int GW = (NN + 3) / 4;       // wave-per-node gather grid

  // ---- layer 0
  split_bf<<<(N4 + 255) / 256, 256, 0, stream>>>(features, Ah, Al, N4);
  gemm_bf16x3<128, 1><<<gbig, 256, 0, stream>>>(Ah, Al, Wp0h, Wp0l, b0, nullptr, ftb, NN, 256);
  attn_scores4_bf<<<(NN + 3) / 4, 256, 0, stream>>>(ftb, al0, alb0, ar0, arb0, a1, a2, NN);
  gather_wave4<<<GW, 256, 0, stream>>>(ftb, a1, a2, nullptr, row_ptr, eidx, src, Ah, Al);

  // ---- layer 1 (residual): gathers write Ah/Al for the next GEMMs
  gemm_bf16x3<128, 1><<<gbig, 256, 0, stream>>>(Ah, Al, Wp1h, Wp1l, b1, nullptr, ftb, NN, 256);
  gemm_bf16x3<128, 0><<<gbig, 256, 0, stream>>>(Ah, Al, Rp1h, Rp1l, Rb1, B3, nullptr, NN, 256);
  attn_scores4_bf<<<(NN + 3) / 4, 256, 0, stream>>>(ftb, al1, alb1, ar1, arb1, a1, a2, NN);
  gather_wave4<<<GW, 256, 0, stream>>>(ftb, a1, a2, B3, row_ptr, eidx, src, Ah, Al);

  // ---- final layer (residual, 1 head, 40 classes)
  gemm_bf16x3<64, 0><<<gsm, 256, 0, stream>>>(Ah, Al, Wfh, Wfl, bfc, B1, nullptr, NN, NCLS);
  gemm_bf16x3<64, 0><<<gsm, 256, 0, stream>>>(Ah, Al, Rfh, Rfl, Rbf, B2, nullptr, NN, NCLS);
  attn_scores1<<<(NN + 3) / 4, 256, 0, stream>>>(B1, alf, alfb, arf, arfb, a1, a2, NN);
  gather_fused1<<<NN, 64, 0, stream>>>(B1, a1, a2, B2, row_ptr, eidx, src, out);
}

// Round 9
// 641.274 us; speedup vs baseline: 1.1642x; 1.1642x over previous
//
#include <hip/hip_runtime.h>
#include <hip/hip_bf16.h>
#include <math.h>

#define NN   50000
#define NE   800000
#define NHEAD 4
#define HIDD 64
#define DD   256   // NHEAD*HIDD
#define NCLS 40

typedef __attribute__((ext_vector_type(8))) short s8v;    // 8 x bf16 bits
typedef __attribute__((ext_vector_type(4))) float f4v;

static __device__ __forceinline__ float elu_f(float x) {
  return x > 0.f ? x : expm1f(x);
}
static __device__ __forceinline__ float lrelu_exp(float x) {
  float v = x > 0.f ? x : 0.01f * x;
  return expf(v);
}
static __device__ __forceinline__ unsigned short f2bf(float x) {
  union { float f; unsigned u; } v; v.f = x;
  unsigned r = v.u + 0x7fffu + ((v.u >> 16) & 1u);   // RNE
  return (unsigned short)(r >> 16);
}
static __device__ __forceinline__ float bf2f(unsigned short b) {
  union { unsigned u; float f; } v; v.u = ((unsigned)b) << 16;
  return v.f;
}
static __device__ __forceinline__ float rdlanef(float v, int l) {
  return __uint_as_float(__builtin_amdgcn_readlane(__float_as_uint(v), l));
}

// ---- one launch packs all weights to bf16 hi/lo [n][k]; final Wf+Rf merged
// into one [128][256] operand (cols 0..63 = Wf-padded, 64..127 = Rf-padded).
__global__ void pack_all(const float* __restrict__ W0, const float* __restrict__ W1,
                         const float* __restrict__ R1, const float* __restrict__ Wf,
                         const float* __restrict__ Rf,
                         unsigned short* __restrict__ Wp0h, unsigned short* __restrict__ Wp0l,
                         unsigned short* __restrict__ Wp1h, unsigned short* __restrict__ Wp1l,
                         unsigned short* __restrict__ Rp1h, unsigned short* __restrict__ Rp1l,
                         unsigned short* __restrict__ WfRh, unsigned short* __restrict__ WfRl) {
  int bid = blockIdx.x;
  const float* S = nullptr; unsigned short *Bh, *Bl; int big;
  if (bid < 256)      { S = W0; Bh = Wp0h; Bl = Wp0l; big = 1; }
  else if (bid < 512) { S = W1; Bh = Wp1h; Bl = Wp1l; big = 1; bid -= 256; }
  else if (bid < 768) { S = R1; Bh = Rp1h; Bl = Rp1l; big = 1; bid -= 512; }
  else                { Bh = WfRh; Bl = WfRl; big = 0; bid -= 768; }   // 128 blocks
  int i = bid * 256 + threadIdx.x;       // i = n*256 + k
  int n = i >> 8, k = i & 255;
  float v;
  if (big) {
    v = S[(n >> 6) * (256 * 64) + k * 64 + (n & 63)];                  // [H][256][64]
  } else {
    int cc = n & 63;
    const float* SS = (n < 64) ? Wf : Rf;                              // [256][40]
    v = (cc < NCLS) ? SS[k * NCLS + cc] : 0.f;
  }
  unsigned short hi = f2bf(v);
  Bh[i] = hi;
  Bl[i] = f2bf(v - bf2f(hi));
}

// ---- split fp32 [*][256] -> bf16 hi/lo (features only)
__global__ void split_bf(const float* __restrict__ A,
                         unsigned short* __restrict__ Ah,
                         unsigned short* __restrict__ Al, int n4) {
  int i = blockIdx.x * 256 + threadIdx.x;
  if (i >= n4) return;
  float4 v = ((const float4*)A)[i];
  ushort4 h, l;
  h.x = f2bf(v.x); l.x = f2bf(v.x - bf2f(h.x));
  h.y = f2bf(v.y); l.y = f2bf(v.y - bf2f(h.y));
  h.z = f2bf(v.z); l.z = f2bf(v.z - bf2f(h.z));
  h.w = f2bf(v.w); l.w = f2bf(v.w - bf2f(h.w));
  ((ushort4*)Ah)[i] = h;
  ((ushort4*)Al)[i] = l;
}

// ---- bf16x3 MFMA GEMM: C = A[M x 256] @ Bt^T + bias
// MODE 0: fp32 out (stride Nc). MODE 1: bf16 out (stride Nc).
// MODE 2: dual fp32 out, Nc=128 merged [Wf|Rf]: col<64 -> C, col>=64 -> C2,
//         both with row stride NCLS, column (col&63)<NCLS.
template <int BN, int MODE>
__global__ __launch_bounds__(256) void gemm_bf16x3(
    const unsigned short* __restrict__ Ah, const unsigned short* __restrict__ Al,
    const unsigned short* __restrict__ Bth, const unsigned short* __restrict__ Btl,
    const float* __restrict__ bias, const float* __restrict__ bias2,
    float* __restrict__ C, float* __restrict__ C2,
    unsigned short* __restrict__ Cb,
    int M, int Nc) {
  constexpr int K = 256;
  constexpr int RS = 40;                 // LDS row stride (ushorts): 80B -> 2-way max
  constexpr int WM = (BN == 128) ? 2 : 4;   // waves along M
  constexpr int WN = 4 / WM;                // waves along N
  constexpr int MI = (128 / WM) / 16;       // 4 or 2
  constexpr int NI = (BN / WN) / 16;        // 4

  __shared__ unsigned short sAh[128 * RS];
  __shared__ unsigned short sAl[128 * RS];
  __shared__ unsigned short sBh[BN * RS];
  __shared__ unsigned short sBl[BN * RS];

  const int tid = threadIdx.x;
  const int lane = tid & 63;
  const int w = tid >> 6;
  const int wr = w / WN, wc = w % WN;
  const int rowbase = wr * (128 / WM);
  const int colbase = wc * (BN / WN);
  const int row0 = blockIdx.x * 128;
  const int col0 = blockIdx.y * BN;
  const int lm = lane & 15;
  const int lk8 = (lane >> 4) * 8;

  f4v acc[MI][NI];
#pragma unroll
  for (int i = 0; i < MI; i++)
#pragma unroll
    for (int j = 0; j < NI; j++) acc[i][j] = (f4v)(0.f);

  for (int k0 = 0; k0 < K; k0 += 32) {
    __syncthreads();
    // stage A 128x32 bf16 hi/lo (pre-split)
#pragma unroll
    for (int i = 0; i < 2; ++i) {
      int idx = tid + i * 256;            // 0..511
      int r = idx >> 2, seg = idx & 3;
      int grow = row0 + r;
      s8v hv = (s8v)(short)0, lv = (s8v)(short)0;
      if (grow < M) {
        size_t g = (size_t)grow * K + k0 + seg * 8;
        hv = *(const s8v*)(Ah + g);
        lv = *(const s8v*)(Al + g);
      }
      *(s8v*)&sAh[r * RS + seg * 8] = hv;
      *(s8v*)&sAl[r * RS + seg * 8] = lv;
    }
    // stage B BNx32 bf16 hi/lo (pre-transposed [n][k])
#pragma unroll
    for (int i = 0; i < BN / 64; ++i) {
      int idx = tid + i * 256;            // < BN*4
      int n = idx >> 2, seg = idx & 3;
      size_t g = (size_t)(col0 + n) * K + k0 + seg * 8;
      *(s8v*)&sBh[n * RS + seg * 8] = *(const s8v*)(Bth + g);
      *(s8v*)&sBl[n * RS + seg * 8] = *(const s8v*)(Btl + g);
    }
    __syncthreads();

    s8v ah[MI], al_[MI], bh[NI], bl_[NI];
#pragma unroll
    for (int mi = 0; mi < MI; ++mi) {
      int base = (rowbase + mi * 16 + lm) * RS + lk8;
      ah[mi] = *(const s8v*)&sAh[base];
      al_[mi] = *(const s8v*)&sAl[base];
    }
#pragma unroll
    for (int ni = 0; ni < NI; ++ni) {
      int base = (colbase + ni * 16 + lm) * RS + lk8;
      bh[ni] = *(const s8v*)&sBh[base];
      bl_[ni] = *(const s8v*)&sBl[base];
    }
    // pass 1: hi*hi
#pragma unroll
    for (int mi = 0; mi < MI; ++mi)
#pragma unroll
      for (int ni = 0; ni < NI; ++ni)
        acc[mi][ni] = __builtin_amdgcn_mfma_f32_16x16x32_bf16(ah[mi], bh[ni], acc[mi][ni], 0, 0, 0);
    // pass 2: hi*lo
#pragma unroll
    for (int mi = 0; mi < MI; ++mi)
#pragma unroll
      for (int ni = 0; ni < NI; ++ni)
        acc[mi][ni] = __builtin_amdgcn_mfma_f32_16x16x32_bf16(ah[mi], bl_[ni], acc[mi][ni], 0, 0, 0);
    // pass 3: lo*hi
#pragma unroll
    for (int mi = 0; mi < MI; ++mi)
#pragma unroll
      for (int ni = 0; ni < NI; ++ni)
        acc[mi][ni] = __builtin_amdgcn_mfma_f32_16x16x32_bf16(al_[mi], bh[ni], acc[mi][ni], 0, 0, 0);
  }

  // epilogue  (D map: col=lane&15, row=(lane>>4)*4+r)
#pragma unroll
  for (int ni = 0; ni < NI; ++ni) {
    int col = col0 + colbase + ni * 16 + lm;
    if (MODE != 2) {
      if (col >= Nc) continue;
      float bv = bias[col];
#pragma unroll
      for (int mi = 0; mi < MI; ++mi) {
        int rbase = row0 + rowbase + mi * 16 + (lane >> 4) * 4;
#pragma unroll
        for (int r = 0; r < 4; ++r) {
          int row = rbase + r;
          if (row < M) {
            float o = acc[mi][ni][r] + bv;
            if (MODE == 1) Cb[(size_t)row * Nc + col] = f2bf(o);
            else           C[(size_t)row * Nc + col] = o;
          }
        }
      }
    } else {
      int cc = col & 63;
      if (cc >= NCLS) continue;
      float bv = (col < 64) ? bias[cc] : bias2[cc];
      float* dstp = (col < 64) ? C : C2;
#pragma unroll
      for (int mi = 0; mi < MI; ++mi) {
        int rbase = row0 + rowbase + mi * 16 + (lane >> 4) * 4;
#pragma unroll
        for (int r = 0; r < 4; ++r) {
          int row = rbase + r;
          if (row < M) dstp[(size_t)row * NCLS + cc] = acc[mi][ni][r] + bv;
        }
      }
    }
  }
}

// ---- per-node attention scores from bf16 ft, 4 heads over 256 dims
__global__ void attn_scores4_bf(const unsigned short* __restrict__ ftb,
                                const float* __restrict__ al, const float* __restrict__ alb,
                                const float* __restrict__ ar, const float* __restrict__ arb,
                                float* __restrict__ a1, float* __restrict__ a2, int n_nodes) {
  int n = blockIdx.x * 4 + (threadIdx.x >> 6);
  if (n >= n_nodes) return;
  int lane = threadIdx.x & 63;
  ushort4 fb = *(const ushort4*)(ftb + (size_t)n * 256 + lane * 4);
  float4 f = make_float4(bf2f(fb.x), bf2f(fb.y), bf2f(fb.z), bf2f(fb.w));
  float4 l4 = *(const float4*)(al + lane * 4);
  float4 r4 = *(const float4*)(ar + lane * 4);
  float p1 = f.x * l4.x + f.y * l4.y + f.z * l4.z + f.w * l4.w;
  float p2 = f.x * r4.x + f.y * r4.y + f.z * r4.z + f.w * r4.w;
#pragma unroll
  for (int m = 1; m < 16; m <<= 1) {
    p1 += __shfl_xor(p1, m);
    p2 += __shfl_xor(p2, m);
  }
  if ((lane & 15) == 0) {
    int h = lane >> 4;
    a1[n * 4 + h] = p1 + alb[h];
    a2[n * 4 + h] = p2 + arb[h];
  }
}

// ---- final-layer attention scores (1 head over 40 dims, fp32 ft)
__global__ void attn_scores1(const float* __restrict__ ftf,
                             const float* __restrict__ alf, const float* __restrict__ alfb,
                             const float* __restrict__ arf, const float* __restrict__ arfb,
                             float* __restrict__ a1, float* __restrict__ a2, int n_nodes) {
  int n = blockIdx.x * 4 + (threadIdx.x >> 6);
  if (n >= n_nodes) return;
  int lane = threadIdx.x & 63;
  float v = (lane < NCLS) ? ftf[(size_t)n * NCLS + lane] : 0.f;
  float p1 = (lane < NCLS) ? v * alf[lane] : 0.f;
  float p2 = (lane < NCLS) ? v * arf[lane] : 0.f;
#pragma unroll
  for (int m = 1; m < 64; m <<= 1) {
    p1 += __shfl_xor(p1, m);
    p2 += __shfl_xor(p2, m);
  }
  if (lane == 0) {
    a1[n] = p1 + alfb[0];
    a2[n] = p2 + arfb[0];
  }
}

// ---- CSR build
__global__ void count_deg(const int* __restrict__ dst, int* __restrict__ deg) {
  int e = blockIdx.x * blockDim.x + threadIdx.x;
  if (e < NE) atomicAdd(&deg[dst[e]], 1);
}

// hierarchical scan: 1024 elems per block
__global__ void scan_part(const int* __restrict__ deg, int* __restrict__ bsum, int n) {
  __shared__ int red[256];
  int t = threadIdx.x;
  int base = blockIdx.x * 1024 + t * 4;
  int s = 0;
#pragma unroll
  for (int j = 0; j < 4; ++j) {
    int idx = base + j;
    if (idx < n) s += deg[idx];
  }
  red[t] = s;
  __syncthreads();
  for (int off = 128; off > 0; off >>= 1) {
    if (t < off) red[t] += red[t + off];
    __syncthreads();
  }
  if (t == 0) bsum[blockIdx.x] = red[0];
}

__global__ void scan_top(const int* __restrict__ bsum, int* __restrict__ boff, int nb) {
  if (threadIdx.x == 0) {
    int run = 0;
    for (int i = 0; i < nb; ++i) { boff[i] = run; run += bsum[i]; }
  }
}

__global__ void scan_write(const int* __restrict__ deg, const int* __restrict__ boff,
                           int* __restrict__ row_ptr, int* __restrict__ cursor, int n) {
  __shared__ int tsum[256];
  int t = threadIdx.x;
  int base = blockIdx.x * 1024 + t * 4;
  int d0 = 0, d1 = 0, d2 = 0, d3 = 0;
  if (base + 0 < n) d0 = deg[base + 0];
  if (base + 1 < n) d1 = deg[base + 1];
  if (base + 2 < n) d2 = deg[base + 2];
  if (base + 3 < n) d3 = deg[base + 3];
  int s = d0 + d1 + d2 + d3;
  tsum[t] = s;
  __syncthreads();
  for (int off = 1; off < 256; off <<= 1) {
    int u = (t >= off) ? tsum[t - off] : 0;
    __syncthreads();
    tsum[t] += u;
    __syncthreads();
  }
  int excl = boff[blockIdx.x] + tsum[t] - s;   // exclusive prefix for my 4
  if (base + 0 < n) { cursor[base + 0] = excl; excl += d0; row_ptr[base + 1] = excl; }
  if (base + 1 < n) { cursor[base + 1] = excl; excl += d1; row_ptr[base + 2] = excl; }
  if (base + 2 < n) { cursor[base + 2] = excl; excl += d2; row_ptr[base + 3] = excl; }
  if (base + 3 < n) { cursor[base + 3] = excl; excl += d3; row_ptr[base + 4] = excl; }
  if (blockIdx.x == 0 && t == 0) row_ptr[0] = 0;
}

__global__ void scatter_e(const int* __restrict__ dst, int* __restrict__ cursor,
                          int* __restrict__ eidx) {
  int e = blockIdx.x * blockDim.x + threadIdx.x;
  if (e >= NE) return;
  int d = dst[e];
  int pos = atomicAdd(&cursor[d], 1);
  eidx[pos] = e;
}

// ---- wave-per-node fused gather (4 heads, D=256), bf16 ft.
__global__ __launch_bounds__(256) void gather_wave4(
    const unsigned short* __restrict__ ftb, const float* __restrict__ a1,
    const float* __restrict__ a2, const float* __restrict__ res,
    const int* __restrict__ row_ptr, const int* __restrict__ eidx,
    const int* __restrict__ src,
    unsigned short* __restrict__ outh, unsigned short* __restrict__ outl) {
  __shared__ float s_w[4][64][4];
  const int wid = threadIdx.x >> 6;
  const int n = blockIdx.x * 4 + wid;
  if (n >= NN) return;
  const int lane = threadIdx.x & 63;
  const int h = lane >> 4;            // head for my 4 columns
  const int b = row_ptr[n], en = row_ptr[n + 1];
  const int deg = en - b;
  const float4 a1v = *(const float4*)(a1 + (size_t)n * 4);
  float4 accv = make_float4(0.f, 0.f, 0.f, 0.f);
  float den = 0.f;

  for (int cb = 0; cb < deg; cb += 64) {
    int cnt = min(64, deg - cb);
    int s = 0;
    if (lane < cnt) {
      s = src[eidx[b + cb + lane]];
      float4 as_ = *(const float4*)(a2 + (size_t)s * 4);
      float4 w4;
      w4.x = lrelu_exp(as_.x + a1v.x);
      w4.y = lrelu_exp(as_.y + a1v.y);
      w4.z = lrelu_exp(as_.z + a1v.z);
      w4.w = lrelu_exp(as_.w + a1v.w);
      *(float4*)&s_w[wid][lane][0] = w4;
    }
    asm volatile("s_waitcnt lgkmcnt(0)" ::: "memory");
    int i = 0;
    for (; i + 8 <= cnt; i += 8) {
      int s0 = __builtin_amdgcn_readlane(s, i + 0);
      int s1 = __builtin_amdgcn_readlane(s, i + 1);
      int s2 = __builtin_amdgcn_readlane(s, i + 2);
      int s3 = __builtin_amdgcn_readlane(s, i + 3);
      int s4 = __builtin_amdgcn_readlane(s, i + 4);
      int s5 = __builtin_amdgcn_readlane(s, i + 5);
      int s6 = __builtin_amdgcn_readlane(s, i + 6);
      int s7 = __builtin_amdgcn_readlane(s, i + 7);
      float w0 = s_w[wid][i + 0][h];
      float w1 = s_w[wid][i + 1][h];
      float w2 = s_w[wid][i + 2][h];
      float w3 = s_w[wid][i + 3][h];
      float w4_ = s_w[wid][i + 4][h];
      float w5 = s_w[wid][i + 5][h];
      float w6 = s_w[wid][i + 6][h];
      float w7 = s_w[wid][i + 7][h];
      ushort4 f0 = *(const ushort4*)(ftb + (size_t)s0 * DD + lane * 4);
      ushort4 f1 = *(const ushort4*)(ftb + (size_t)s1 * DD + lane * 4);
      ushort4 f2 = *(const ushort4*)(ftb + (size_t)s2 * DD + lane * 4);
      ushort4 f3 = *(const ushort4*)(ftb + (size_t)s3 * DD + lane * 4);
      ushort4 f4 = *(const ushort4*)(ftb + (size_t)s4 * DD + lane * 4);
      ushort4 f5 = *(const ushort4*)(ftb + (size_t)s5 * DD + lane * 4);
      ushort4 f6 = *(const ushort4*)(ftb + (size_t)s6 * DD + lane * 4);
      ushort4 f7 = *(const ushort4*)(ftb + (size_t)s7 * DD + lane * 4);
      accv.x = fmaf(bf2f(f0.x), w0, accv.x);
      accv.y = fmaf(bf2f(f0.y), w0, accv.y);
      accv.z = fmaf(bf2f(f0.z), w0, accv.z);
      accv.w = fmaf(bf2f(f0.w), w0, accv.w);
      accv.x = fmaf(bf2f(f1.x), w1, accv.x);
      accv.y = fmaf(bf2f(f1.y), w1, accv.y);
      accv.z = fmaf(bf2f(f1.z), w1, accv.z);
      accv.w = fmaf(bf2f(f1.w), w1, accv.w);
      accv.x = fmaf(bf2f(f2.x), w2, accv.x);
      accv.y = fmaf(bf2f(f2.y), w2, accv.y);
      accv.z = fmaf(bf2f(f2.z), w2, accv.z);
      accv.w = fmaf(bf2f(f2.w), w2, accv.w);
      accv.x = fmaf(bf2f(f3.x), w3, accv.x);
      accv.y = fmaf(bf2f(f3.y), w3, accv.y);
      accv.z = fmaf(bf2f(f3.z), w3, accv.z);
      accv.w = fmaf(bf2f(f3.w), w3, accv.w);
      accv.x = fmaf(bf2f(f4.x), w4_, accv.x);
      accv.y = fmaf(bf2f(f4.y), w4_, accv.y);
      accv.z = fmaf(bf2f(f4.z), w4_, accv.z);
      accv.w = fmaf(bf2f(f4.w), w4_, accv.w);
      accv.x = fmaf(bf2f(f5.x), w5, accv.x);
      accv.y = fmaf(bf2f(f5.y), w5, accv.y);
      accv.z = fmaf(bf2f(f5.z), w5, accv.z);
      accv.w = fmaf(bf2f(f5.w), w5, accv.w);
      accv.x = fmaf(bf2f(f6.x), w6, accv.x);
      accv.y = fmaf(bf2f(f6.y), w6, accv.y);
      accv.z = fmaf(bf2f(f6.z), w6, accv.z);
      accv.w = fmaf(bf2f(f6.w), w6, accv.w);
      accv.x = fmaf(bf2f(f7.x), w7, accv.x);
      accv.y = fmaf(bf2f(f7.y), w7, accv.y);
      accv.z = fmaf(bf2f(f7.z), w7, accv.z);
      accv.w = fmaf(bf2f(f7.w), w7, accv.w);
      den += ((w0 + w1) + (w2 + w3)) + ((w4_ + w5) + (w6 + w7));
    }
    for (; i < cnt; ++i) {
      int si = __builtin_amdgcn_readlane(s, i);
      float wi = s_w[wid][i][h];
      ushort4 fv = *(const ushort4*)(ftb + (size_t)si * DD + lane * 4);
      accv.x = fmaf(bf2f(fv.x), wi, accv.x);
      accv.y = fmaf(bf2f(fv.y), wi, accv.y);
      accv.z = fmaf(bf2f(fv.z), wi, accv.z);
      accv.w = fmaf(bf2f(fv.w), wi, accv.w);
      den += wi;
    }
  }
  float invden = (deg > 0) ? 1.f / den : 0.f;
  float4 r = (res != nullptr) ? *(const float4*)(res + (size_t)n * DD + lane * 4)
                              : make_float4(0.f, 0.f, 0.f, 0.f);
  float4 o;
  o.x = elu_f(r.x + accv.x * invden);
  o.y = elu_f(r.y + accv.y * invden);
  o.z = elu_f(r.z + accv.z * invden);
  o.w = elu_f(r.w + accv.w * invden);
  ushort4 hh, ll;
  hh.x = f2bf(o.x); ll.x = f2bf(o.x - bf2f(hh.x));
  hh.y = f2bf(o.y); ll.y = f2bf(o.y - bf2f(hh.y));
  hh.z = f2bf(o.z); ll.z = f2bf(o.z - bf2f(hh.z));
  hh.w = f2bf(o.w); ll.w = f2bf(o.w - bf2f(hh.w));
  *(ushort4*)(outh + (size_t)n * DD + lane * 4) = hh;
  *(ushort4*)(outl + (size_t)n * DD + lane * 4) = ll;
}

// ---- fused gather (1 head, D=NCLS=40), fp32 ft, 8x-unrolled
__global__ __launch_bounds__(64) void gather_fused1(
    const float* __restrict__ ft, const float* __restrict__ a1,
    const float* __restrict__ a2, const float* __restrict__ res,
    const int* __restrict__ row_ptr, const int* __restrict__ eidx,
    const int* __restrict__ src, float* __restrict__ out) {
  const int n = blockIdx.x;
  const int d = threadIdx.x;
  const int b = row_ptr[n], en = row_ptr[n + 1];
  const int deg = en - b;
  const float a1n = a1[n];
  float acc = 0.f;
  float den = 0.f;

  for (int cb = 0; cb < deg; cb += 64) {
    int cnt = min(64, deg - cb);
    int s = 0;
    float wv = 0.f;
    if (d < cnt) {
      s = src[eidx[b + cb + d]];
      wv = lrelu_exp(a2[s] + a1n);
    }
    int i = 0;
    for (; i + 8 <= cnt; i += 8) {
      int s0 = __builtin_amdgcn_readlane(s, i + 0);
      int s1 = __builtin_amdgcn_readlane(s, i + 1);
      int s2 = __builtin_amdgcn_readlane(s, i + 2);
      int s3 = __builtin_amdgcn_readlane(s, i + 3);
      int s4 = __builtin_amdgcn_readlane(s, i + 4);
      int s5 = __builtin_amdgcn_readlane(s, i + 5);
      int s6 = __builtin_amdgcn_readlane(s, i + 6);
      int s7 = __builtin_amdgcn_readlane(s, i + 7);
      float w0 = rdlanef(wv, i + 0), w1 = rdlanef(wv, i + 1);
      float w2 = rdlanef(wv, i + 2), w3 = rdlanef(wv, i + 3);
      float w4_ = rdlanef(wv, i + 4), w5 = rdlanef(wv, i + 5);
      float w6 = rdlanef(wv, i + 6), w7 = rdlanef(wv, i + 7);
      if (d < NCLS) {
        float v0 = ft[(size_t)s0 * NCLS + d];
        float v1 = ft[(size_t)s1 * NCLS + d];
        float v2 = ft[(size_t)s2 * NCLS + d];
        float v3 = ft[(size_t)s3 * NCLS + d];
        float v4 = ft[(size_t)s4 * NCLS + d];
        float v5 = ft[(size_t)s5 * NCLS + d];
        float v6 = ft[(size_t)s6 * NCLS + d];
        float v7 = ft[(size_t)s7 * NCLS + d];
        acc = fmaf(v0, w0, acc);
        acc = fmaf(v1, w1, acc);
        acc = fmaf(v2, w2, acc);
        acc = fmaf(v3, w3, acc);
        acc = fmaf(v4, w4_, acc);
        acc = fmaf(v5, w5, acc);
        acc = fmaf(v6, w6, acc);
        acc = fmaf(v7, w7, acc);
      }
      den += ((w0 + w1) + (w2 + w3)) + ((w4_ + w5) + (w6 + w7));
    }
    for (; i < cnt; ++i) {
      int si = __builtin_amdgcn_readlane(s, i);
      float wi = rdlanef(wv, i);
      if (d < NCLS) acc = fmaf(ft[(size_t)si * NCLS + d], wi, acc);
      den += wi;
    }
  }
  float invden = (deg > 0) ? 1.f / den : 0.f;
  if (d < NCLS) {
    float r = res[(size_t)n * NCLS + d];
    out[(size_t)n * NCLS + d] = elu_f(r + acc * invden);
  }
}

extern "C" void kernel_launch(void* const* d_in, const int* in_sizes, int n_in,
                              void* d_out, int out_size, void* d_ws, size_t ws_size,
                              hipStream_t stream) {
  const float* features = (const float*)d_in[0];
  const int* src = (const int*)d_in[1];
  const int* dst = (const int*)d_in[2];
  const float* W0 = (const float*)d_in[3];
  const float* b0 = (const float*)d_in[4];
  const float* al0 = (const float*)d_in[5];
  const float* alb0 = (const float*)d_in[6];
  const float* ar0 = (const float*)d_in[7];
  const float* arb0 = (const float*)d_in[8];
  const float* W1 = (const float*)d_in[9];
  const float* b1 = (const float*)d_in[10];
  const float* al1 = (const float*)d_in[11];
  const float* alb1 = (const float*)d_in[12];
  const float* ar1 = (const float*)d_in[13];
  const float* arb1 = (const float*)d_in[14];
  const float* R1 = (const float*)d_in[15];
  const float* Rb1 = (const float*)d_in[16];
  const float* Wf = (const float*)d_in[17];
  const float* bfc = (const float*)d_in[18];
  const float* alf = (const float*)d_in[19];
  const float* alfb = (const float*)d_in[20];
  const float* arf = (const float*)d_in[21];
  const float* arfb = (const float*)d_in[22];
  const float* Rf = (const float*)d_in[23];
  const float* Rbf = (const float*)d_in[24];
  float* out = (float*)d_out;

  float* p = (float*)d_ws;
  float* B1 = p;  p += (size_t)NN * 256;   // final ft (fp32, stride NCLS used)
  float* B2 = p;  p += (size_t)NN * 256;   // final res (fp32, stride NCLS used)
  float* B3 = p;  p += (size_t)NN * 256;   // layer-1 residual (fp32)
  float* a1 = p;  p += (size_t)NN * 4;
  float* a2 = p;  p += (size_t)NN * 4;
  unsigned short* us = (unsigned short*)p;
  unsigned short* Wp0h = us; us += 65536;
  unsigned short* Wp0l = us; us += 65536;
  unsigned short* Wp1h = us; us += 65536;
  unsigned short* Wp1l = us; us += 65536;
  unsigned short* Rp1h = us; us += 65536;
  unsigned short* Rp1l = us; us += 65536;
  unsigned short* WfRh = us; us += 128 * 256;
  unsigned short* WfRl = us; us += 128 * 256;
  unsigned short* Ah = us;   us += (size_t)NN * 256;
  unsigned short* Al = us;   us += (size_t)NN * 256;
  unsigned short* ftb = us;  us += (size_t)NN * 256;
  int* ip = (int*)us;
  int* row_ptr = ip; ip += NN + 1;
  int* cursor = ip;  ip += NN;
  int* deg = ip;     ip += NN;
  int* eidx = ip;    ip += NE;
  int* bsum = ip;    ip += 64;
  int* boff = ip;    ip += 64;

  const int EB = (NE + 255) / 256;
  const int N4 = NN * 64;            // NN*256/4 float4 elements
  const int GB = (NN + 1023) / 1024; // 49 scan blocks

  // weight packing + bf16 hi/lo split, single launch (768 big + 128 final)
  pack_all<<<896, 256, 0, stream>>>(W0, W1, R1, Wf, Rf,
                                    Wp0h, Wp0l, Wp1h, Wp1l, Rp1h, Rp1l,
                                    WfRh, WfRl);

  // CSR by dst (built once, reused by all 3 layers) -- hierarchical scan
  hipMemsetAsync(deg, 0, NN * sizeof(int), stream);
  count_deg<<<EB, 256, 0, stream>>>(dst, deg);
  scan_part<<<GB, 256, 0, stream>>>(deg, bsum, NN);
  scan_top<<<1, 64, 0, stream>>>(bsum, boff, GB);
  scan_write<<<GB, 256, 0, stream>>>(deg, boff, row_ptr, cursor, NN);
  scatter_e<<<EB, 256, 0, stream>>>(dst, cursor, eidx);

  const int MB = (NN + 127) / 128;   // 391
  dim3 gbig(MB, 2);
  dim3 gsm(MB, 1);
  const int GW = (NN + 3) / 4;       // wave-per-node gather grid

  // ---- layer 0
  split_bf<<<(N4 + 255) / 256, 256, 0, stream>>>(features, Ah, Al, N4);
  gemm_bf16x3<128, 1><<<gbig, 256, 0, stream>>>(Ah, Al, Wp0h, Wp0l, b0, nullptr,
                                                nullptr, nullptr, ftb, NN, 256);
  attn_scores4_bf<<<(NN + 3) / 4, 256, 0, stream>>>(ftb, al0, alb0, ar0, arb0, a1, a2, NN);
  gather_wave4<<<GW, 256, 0, stream>>>(ftb, a1, a2, nullptr, row_ptr, eidx, src, Ah, Al);

  // ---- layer 1 (residual): gathers write Ah/Al for the next GEMMs
  gemm_bf16x3<128, 1><<<gbig, 256, 0, stream>>>(Ah, Al, Wp1h, Wp1l, b1, nullptr,
                                                nullptr, nullptr, ftb, NN, 256);
  gemm_bf16x3<128, 0><<<gbig, 256, 0, stream>>>(Ah, Al, Rp1h, Rp1l, Rb1, nullptr,
                                                B3, nullptr, nullptr, NN, 256);
  attn_scores4_bf<<<(NN + 3) / 4, 256, 0, stream>>>(ftb, al1, alb1, ar1, arb1, a1, a2, NN);
  gather_wave4<<<GW, 256, 0, stream>>>(ftb, a1, a2, B3, row_ptr, eidx, src, Ah, Al);

  // ---- final layer: ONE merged GEMM for [Wf|Rf] -> ft (B1) + res (B2)
  gemm_bf16x3<128, 2><<<gsm, 256, 0, stream>>>(Ah, Al, WfRh, WfRl, bfc, Rbf,
                                               B1, B2, nullptr, NN, 128);
  attn_scores1<<<(NN + 3) / 4, 256, 0, stream>>>(B1, alf, alfb, arf, arfb, a1, a2, NN);
  gather_fused1<<<NN, 64, 0, stream>>>(B1, a1, a2, B2, row_ptr, eidx, src, out);
}